// Round 8
// baseline (402.700 us; speedup 1.0000x reference)
//
#include <hip/hip_runtime.h>
#include <math.h>

#define N_TOK   16384
#define D_MODEL 4096
#define N_EXP   16
#define N_SEL   4
#define WELEM   (N_EXP * D_MODEL)   // 65536 per weight matrix
#define TILES   2                   // token tiles per block (32 tokens)
#define NWIN    16                  // k-windows
#define WINF    256                 // floats per token per window (1 KB run)
#define TSTR    260                 // padded words per token row in window buf
#define BUFW    (32 * TSTR)         // 8320 words per staging buffer

typedef __bf16 bf16x8 __attribute__((ext_vector_type(8)));
typedef float  f32x4  __attribute__((ext_vector_type(4)));

#define MFMA(a, b, c) __builtin_amdgcn_mfma_f32_16x16x32_bf16((a), (b), (c), 0, 0, 0)

// Non-temporal float4 load: x is a 268-MB single-use stream. Routed around
// the cache hierarchy (nt bit) so it runs at HBM stream rate instead of
// thrashing the Infinity Cache read path (~1.9 TB/s measured R0-R6).
// NOTE: __builtin_nontemporal_load requires scalar/ext_vector types --
// HIP_vector_type (float4) is rejected (R7 compile fail). Go through f32x4.
__device__ __forceinline__ float4 ntload4(const float* p)
{
    const f32x4 v = __builtin_nontemporal_load((const f32x4*)p);
    return make_float4(v[0], v[1], v[2], v[3]);
}

// ---------------------------------------------------------------------------
// Split w1/wn into bf16 (hi, mid, lo) triplets: w ≈ hi + mid + lo, residual
// ≤ 2^-24 relative. Layout in wbuf: [w1hi][w1mid][w1lo][wnhi][wnmid][wnlo].
// Also zeroes the g_imp/g_load accumulators (replaces a memset dispatch).
// ---------------------------------------------------------------------------
__global__ __launch_bounds__(256) void wprep_kernel(const float* __restrict__ w1,
                                                    const float* __restrict__ wn,
                                                    __bf16* __restrict__ wbuf,
                                                    float* __restrict__ g_acc)
{
    const int i = blockIdx.x * 256 + threadIdx.x;   // 0..65535
    if (blockIdx.x == 0 && threadIdx.x < 2 * N_EXP) g_acc[threadIdx.x] = 0.f;
    {
        const float v = w1[i];
        const __bf16 h = (__bf16)v;  const float r1 = v - (float)h;
        const __bf16 m = (__bf16)r1; const float r2 = r1 - (float)m;
        wbuf[i] = h; wbuf[WELEM + i] = m; wbuf[2 * WELEM + i] = (__bf16)r2;
    }
    {
        const float v = wn[i];
        const __bf16 h = (__bf16)v;  const float r1 = v - (float)h;
        const __bf16 m = (__bf16)r1; const float r2 = r1 - (float)m;
        wbuf[3 * WELEM + i] = h; wbuf[4 * WELEM + i] = m; wbuf[5 * WELEM + i] = (__bf16)r2;
    }
}

// Triple-split one 8-float x chunk into bf16 hi/mid/lo fragments.
__device__ __forceinline__ void split8(const float4 a, const float4 b,
                                       bf16x8& h, bf16x8& m, bf16x8& l)
{
    const float v[8] = {a.x, a.y, a.z, a.w, b.x, b.y, b.z, b.w};
    #pragma unroll
    for (int j = 0; j < 8; ++j) {
        const float vv = v[j];
        const __bf16 hh = (__bf16)vv;  const float r1 = vv - (float)hh;
        const __bf16 mm = (__bf16)r1;  const float r2 = r1 - (float)mm;
        h[j] = hh; m[j] = mm; l[j] = (__bf16)r2;
    }
}

// ---------------------------------------------------------------------------
// Fused gate kernel: block = 32 tokens, 8 waves, grid 512, 2 blocks/CU.
// ROUND 8 = ROUND 7 retry (compile fix only): x stage loads NON-TEMPORAL.
// Theory: gate's FETCH_SIZE (142 MB < x's 268 MB) shows x is partially
// L3-resident across iterations and the kernel is bound by the L3/cache
// READ path (~1.9 TB/s sustained), not by HBM, pattern, sync, or compute
// (R1-R6 all null). nt-loads stream x straight from HBM and stop it
// churning the Infinity Cache. Weights keep normal (cached) loads: 512x
// reuse. Everything else identical to R6.
// A-frag: A[m=lane&15][k=(lane>>4)*8+j]; B-frag: B[k=(lane>>4)*8+j][n=lane&15];
// C/D: col(token)=lane&15, row(expert)=(lane>>4)*4+reg.   (HW-verified layouts)
// ---------------------------------------------------------------------------
__global__ __launch_bounds__(512, 4) void gate_kernel(
    const float* __restrict__ x, const __bf16* __restrict__ wbuf,
    const float* __restrict__ w2, const float* __restrict__ noise,
    float* __restrict__ out, float* __restrict__ g_imp, float* __restrict__ g_load)
{
    __shared__ float smem[2 * BUFW];     // staging dbuf; reused as red/dsum
    __shared__ float s_imp[N_EXP], s_ld[N_EXP];

    const int tid  = threadIdx.x;
    const int lane = tid & 63;
    const int wv   = tid >> 6;      // 0..7: k-sub-slice within each window
    const int ml   = lane & 15;     // A-row (expert) / B-col (token-in-tile)
    const int q    = lane >> 4;     // k-group
    const int t0   = blockIdx.x * (TILES * 16);

    const __bf16* w1h = wbuf;
    const __bf16* w1m = wbuf + WELEM;
    const __bf16* w1l = wbuf + 2 * WELEM;
    const __bf16* wnh = wbuf + 3 * WELEM;
    const __bf16* wnm = wbuf + 4 * WELEM;
    const __bf16* wnl = wbuf + 5 * WELEM;

    // weight base for this wave's k-sub-slice; + c*WINF per window
    const int wofc = ml * D_MODEL + wv * 32 + q * 8;

    // ---- staging map: fid = p*512+tid; token = fid>>6, slot = fid&63.
    //      Each wave loads one contiguous 1-KB token run per phase. ----
    int gi0, gi1, gi2, gi3, li0, li1, li2, li3;
    {
#define MAP(P, GI, LI)                                        \
        {   const int fid = (P) * 512 + tid;                  \
            const int tk  = fid >> 6;                         \
            const int sl  = fid & 63;                         \
            GI = (t0 + tk) * D_MODEL + sl * 4;                \
            LI = tk * TSTR + sl * 4;  }
        MAP(0, gi0, li0) MAP(1, gi1, li1) MAP(2, gi2, li2) MAP(3, gi3, li3)
#undef MAP
    }
    // consume offsets: lane reads token (tt*16+ml), words [wv*32+q*8 .. +8)
    const int lr0 = ml * TSTR + wv * 32 + q * 8;
    const int lr1 = (16 + ml) * TSTR + wv * 32 + q * 8;

    f32x4 c1[TILES], c2[TILES];
    #pragma unroll
    for (int tt = 0; tt < TILES; ++tt) {
        c1[tt] = (f32x4){0.f, 0.f, 0.f, 0.f};
        c2[tt] = (f32x4){0.f, 0.f, 0.f, 0.f};
    }

    float* bufA = smem;
    float* bufB = smem + BUFW;

    {   // prologue: stage window 0 into bufA (non-temporal)
        const float4 s0 = ntload4(x + gi0);
        const float4 s1 = ntload4(x + gi1);
        const float4 s2 = ntload4(x + gi2);
        const float4 s3 = ntload4(x + gi3);
        *(float4*)(bufA + li0) = s0;
        *(float4*)(bufA + li1) = s1;
        *(float4*)(bufA + li2) = s2;
        *(float4*)(bufA + li3) = s3;
        __syncthreads();
    }

#define STEP(CUR, NXT, C)                                                     \
    {                                                                          \
        float4 sg0, sg1, sg2, sg3;                                             \
        if ((C) < NWIN - 1) {                                                  \
            const int co = ((C) + 1) * WINF;                                   \
            sg0 = ntload4(x + gi0 + co);                                       \
            sg1 = ntload4(x + gi1 + co);                                       \
            sg2 = ntload4(x + gi2 + co);                                       \
            sg3 = ntload4(x + gi3 + co);                                       \
        }                                                                      \
        const int wo = wofc + (C) * WINF;                                      \
        const bf16x8 a1h = *(const bf16x8*)(w1h + wo);                         \
        const bf16x8 a1m = *(const bf16x8*)(w1m + wo);                         \
        const bf16x8 a1l = *(const bf16x8*)(w1l + wo);                         \
        const bf16x8 a2h = *(const bf16x8*)(wnh + wo);                         \
        const bf16x8 a2m = *(const bf16x8*)(wnm + wo);                         \
        const bf16x8 a2l = *(const bf16x8*)(wnl + wo);                         \
        const float4 xa0 = *(const float4*)((CUR) + lr0);                      \
        const float4 xb0 = *(const float4*)((CUR) + lr0 + 4);                  \
        const float4 xa1 = *(const float4*)((CUR) + lr1);                      \
        const float4 xb1 = *(const float4*)((CUR) + lr1 + 4);                  \
        bf16x8 xh0, xm0, xl0, xh1, xm1, xl1;                                   \
        split8(xa0, xb0, xh0, xm0, xl0);                                       \
        split8(xa1, xb1, xh1, xm1, xl1);                                       \
        c1[0] = MFMA(a1h, xh0, c1[0]);  c2[0] = MFMA(a2h, xh0, c2[0]);         \
        c1[1] = MFMA(a1h, xh1, c1[1]);  c2[1] = MFMA(a2h, xh1, c2[1]);         \
        c1[0] = MFMA(a1h, xm0, c1[0]);  c2[0] = MFMA(a2h, xm0, c2[0]);         \
        c1[1] = MFMA(a1h, xm1, c1[1]);  c2[1] = MFMA(a2h, xm1, c2[1]);         \
        c1[0] = MFMA(a1m, xh0, c1[0]);  c2[0] = MFMA(a2m, xh0, c2[0]);         \
        c1[1] = MFMA(a1m, xh1, c1[1]);  c2[1] = MFMA(a2m, xh1, c2[1]);         \
        c1[0] = MFMA(a1h, xl0, c1[0]);  c2[0] = MFMA(a2h, xl0, c2[0]);         \
        c1[1] = MFMA(a1h, xl1, c1[1]);  c2[1] = MFMA(a2h, xl1, c2[1]);         \
        c1[0] = MFMA(a1l, xh0, c1[0]);  c2[0] = MFMA(a2l, xh0, c2[0]);         \
        c1[1] = MFMA(a1l, xh1, c1[1]);  c2[1] = MFMA(a2l, xh1, c2[1]);         \
        c1[0] = MFMA(a1m, xm0, c1[0]);  c2[0] = MFMA(a2m, xm0, c2[0]);         \
        c1[1] = MFMA(a1m, xm1, c1[1]);  c2[1] = MFMA(a2m, xm1, c2[1]);         \
        if ((C) < NWIN - 1) {                                                  \
            *(float4*)((NXT) + li0) = sg0;                                     \
            *(float4*)((NXT) + li1) = sg1;                                     \
            *(float4*)((NXT) + li2) = sg2;                                     \
            *(float4*)((NXT) + li3) = sg3;                                     \
        }                                                                      \
        __syncthreads();                                                       \
    }

    #pragma unroll
    for (int h = 0; h < NWIN / 2; ++h) {
        STEP(bufA, bufB, 2 * h)
        STEP(bufB, bufA, 2 * h + 1)
    }
#undef STEP

    // ---- reuse staging LDS: red = smem[0..8448), dsum = smem[8448..9504)
    float* red  = smem;
    float* dsum = smem + 8448;

    #pragma unroll
    for (int tt = 0; tt < TILES; ++tt) {
        #pragma unroll
        for (int r = 0; r < 4; ++r) {
            red[((wv * TILES + tt) * 16 + ml) * 33 + q * 4 + r]      = c1[tt][r];
            red[((wv * TILES + tt) * 16 + ml) * 33 + 16 + q * 4 + r] = c2[tt][r];
        }
    }
    __syncthreads();

    // 1024 partial-sum slots, 512 threads: two 8-way reductions each.
    for (int idx = tid; idx < TILES * 512; idx += 512) {
        const int tt = idx >> 9, tk = (idx >> 5) & 15, o = idx & 31;
        float s = 0.f;
        #pragma unroll
        for (int w = 0; w < 8; ++w) s += red[((w * TILES + tt) * 16 + tk) * 33 + o];
        dsum[(tt * 16 + tk) * 33 + o] = s;
    }
    if (tid < N_EXP) { s_imp[tid] = 0.f; s_ld[tid] = 0.f; }
    __syncthreads();

    // ---- per-token epilogue on 32 lanes ----
    if (tid < TILES * 16) {
        const int tt = tid >> 4, tk = tid & 15;
        const int t = t0 + tid;
        float dot[32];
        #pragma unroll
        for (int e = 0; e < 32; ++e) dot[e] = dsum[(tt * 16 + tk) * 33 + e];

        float th[N_EXP], nc[N_EXP];
        #pragma unroll
        for (int e = 0; e < N_EXP; ++e) th[e] = tanhf(dot[e]);
        #pragma unroll
        for (int e = 0; e < N_EXP; ++e) {
            const float v = dot[N_EXP + e];
            nc[e] = fmaxf(v, 0.f) + log1pf(expf(-fabsf(v))) + 0.01f;
        }

        float lg[N_EXP];
        #pragma unroll
        for (int f = 0; f < N_EXP; ++f) {
            float s = 0.f;
            #pragma unroll
            for (int e = 0; e < N_EXP; ++e) s = fmaf(th[e], w2[f * 16 + e], s);
            lg[f] = s;
        }

        float ln[N_EXP], v[N_EXP];
        {
            const float4* nz = (const float4*)(noise + (size_t)t * 16);
            const float4 n0 = nz[0], n1 = nz[1], n2 = nz[2], n3 = nz[3];
            const float nzv[16] = {n0.x, n0.y, n0.z, n0.w, n1.x, n1.y, n1.z, n1.w,
                                   n2.x, n2.y, n2.z, n2.w, n3.x, n3.y, n3.z, n3.w};
            #pragma unroll
            for (int e = 0; e < N_EXP; ++e) {
                ln[e] = nzv[e] * nc[e];
                v[e]  = lg[e] + ln[e];
            }
        }

        // top-5 selection (ties -> lowest index, matching lax.top_k)
        float tv[5]; int ti[5];
        #pragma unroll
        for (int j = 0; j < 5; ++j) {
            float best = -INFINITY; int bi = 0;
            #pragma unroll
            for (int e = 0; e < N_EXP; ++e) {
                bool taken = false;
                #pragma unroll
                for (int jj = 0; jj < 5; ++jj)
                    if (jj < j) taken = taken || (ti[jj] == e);
                if (!taken && v[e] > best) { best = v[e]; bi = e; }
            }
            tv[j] = best; ti[j] = bi;
        }

        const float mx = tv[0];
        float ex[4], ssum = 0.f;
        #pragma unroll
        for (int j = 0; j < 4; ++j) { ex[j] = expf(tv[j] - mx); ssum += ex[j]; }
        const float inv = 1.f / ssum;
        float sc[4];
        #pragma unroll
        for (int j = 0; j < 4; ++j) sc[j] = ex[j] * inv;

        #pragma unroll
        for (int j = 0; j < 4; ++j) atomicAdd(&s_imp[ti[j]], sc[j]);

        const float thr_in = tv[4], thr_out = tv[3];
        #pragma unroll
        for (int e = 0; e < N_EXP; ++e) {
            const bool  is_in = ln[e] > thr_in;
            const float thr   = is_in ? thr_in : thr_out;
            const float z     = (lg[e] - thr) / nc[e];
            const float prob  = 0.5f * (1.f + erff(z * 0.70710678118654752f));
            atomicAdd(&s_ld[e], prob);
        }

        ((float4*)out)[t] = make_float4((float)ti[0], (float)ti[1],
                                        (float)ti[2], (float)ti[3]);
        ((float4*)(out + N_TOK * N_SEL))[t] = make_float4(sc[0], sc[1], sc[2], sc[3]);
    }
    __syncthreads();
    if (tid < N_EXP)            atomicAdd(&g_imp[tid], s_imp[tid]);
    else if (tid < 2 * N_EXP)   atomicAdd(&g_load[tid - N_EXP], s_ld[tid - N_EXP]);
}

// ---------------------------------------------------------------------------
// gate loss = lambda * (cv2(importance) + cv2(load))
// ---------------------------------------------------------------------------
__global__ void loss_kernel(const float* __restrict__ g_imp,
                            const float* __restrict__ g_load,
                            float* __restrict__ out)
{
    if (threadIdx.x == 0 && blockIdx.x == 0) {
        double mi = 0.0, ml = 0.0;
        for (int e = 0; e < N_EXP; ++e) { mi += g_imp[e]; ml += g_load[e]; }
        mi /= N_EXP; ml /= N_EXP;
        double vi = 0.0, vl = 0.0;
        for (int e = 0; e < N_EXP; ++e) {
            const double di = g_imp[e] - mi;  vi += di * di;
            const double dl = g_load[e] - ml; vl += dl * dl;
        }
        vi /= (N_EXP - 1); vl /= (N_EXP - 1);
        const double ci = vi / (mi * mi + 1e-10);
        const double cl = vl / (ml * ml + 1e-10);
        out[N_TOK * N_SEL * 2] = (float)(0.01 * (ci + cl));
    }
}

// ---------------------------------------------------------------------------
extern "C" void kernel_launch(void* const* d_in, const int* in_sizes, int n_in,
                              void* d_out, int out_size, void* d_ws, size_t ws_size,
                              hipStream_t stream)
{
    const float* x     = (const float*)d_in[0];
    const float* w1    = (const float*)d_in[1];
    const float* w2    = (const float*)d_in[2];
    const float* wn    = (const float*)d_in[3];
    const float* noise = (const float*)d_in[4];
    float* out = (float*)d_out;

    __bf16* wbuf  = (__bf16*)d_ws;                              // 6*65536 bf16 = 768 KB
    float*  g_imp = (float*)((char*)d_ws + (1 << 20));          // 32 floats @ 1 MB
    float*  g_load = g_imp + N_EXP;

    wprep_kernel<<<WELEM / 256, 256, 0, stream>>>(w1, wn, wbuf, g_imp);
    gate_kernel<<<N_TOK / (TILES * 16), 512, 0, stream>>>(x, wbuf, w2, noise, out,
                                                          g_imp, g_load);
    loss_kernel<<<1, 64, 0, stream>>>(g_imp, g_load, out);
}